// Round 5
// baseline (324.980 us; speedup 1.0000x reference)
//
#include <hip/hip_runtime.h>
#include <math.h>

// Problem constants (x: [2048, 2048, 3, 3] f32, bits=8)
// channel stride = h*w = 9 floats; group-block = 8 channels * 9 = 72
// consecutive floats; n = 37,748,736 floats = 524,288 group-blocks.
#define HW        9
#define GROUP     8
#define KEEP      4
#define DELTA     127.0f
#define INV_DELTA (1.0f / 127.0f)
#define GB_FLOATS 72

// Wave-tile geometry: each 64-lane wave owns 32 contiguous group-blocks per
// tile and loops over NT tiles with 2 LDS buffers (prefetch i+2 while
// computing i).
#define GB_TILE   32
#define TILE_F    (GB_TILE * GB_FLOATS)   // 2304 floats = 9216 B per tile
#define TILE_CH   (TILE_F / 256)          // 9 chunks of 1024 B (64 lanes x 16 B)
#define CELLS     (GB_TILE * HW)          // 288 cells per tile (4.5 per lane)
#define WPB       4                       // waves per 256-thread block
#define NT        8                       // tiles per wave
// grid: 524288 gb / (32 gb/tile * 8 tiles/wave * 4 waves/block) = 512 blocks
// LDS: 4 waves * 2 bufs * 9216 B = 73,728 B/block -> exactly 2 blocks/CU.

typedef float f32x4 __attribute__((ext_vector_type(4)));

template <int N>
__device__ __forceinline__ void wait_vmcnt() {
    asm volatile("s_waitcnt vmcnt(%0)" :: "n"(N) : "memory");
}

__device__ __forceinline__ unsigned umx(unsigned a, unsigned b) { return a > b ? a : b; }
__device__ __forceinline__ unsigned umn(unsigned a, unsigned b) { return a < b ? a : b; }

// ---------------- Kernel 1: global max|x| ----------------
__global__ void maxabs_kernel(const float4* __restrict__ x, unsigned* __restrict__ ws, int n4) {
    __shared__ float red[4];
    float m = 0.0f;
    int stride = gridDim.x * blockDim.x;
    #pragma unroll 4
    for (int i = blockIdx.x * blockDim.x + threadIdx.x; i < n4; i += stride) {
        float4 v = x[i];
        m = fmaxf(m, fmaxf(fmaxf(fabsf(v.x), fabsf(v.y)),
                           fmaxf(fabsf(v.z), fabsf(v.w))));
    }
    #pragma unroll
    for (int off = 32; off > 0; off >>= 1)
        m = fmaxf(m, __shfl_down(m, off, 64));
    int wave = threadIdx.x >> 6;
    if ((threadIdx.x & 63) == 0) red[wave] = m;
    __syncthreads();
    if (threadIdx.x == 0) {
        float b = fmaxf(fmaxf(red[0], red[1]), fmaxf(red[2], red[3]));
        atomicMax(ws, __float_as_uint(b));   // |x|>=0: float bit order == uint order
    }
}

// Cold bit-exact reference path (identical to the passing kernel):
// t = (float)tanh(double x); y = t/M (f32 div); z = y*127; rint.
__device__ __attribute__((noinline)) float ref_rz(float xx, float M) {
    float td = (float)tanh((double)xx);
    float y  = td / M;
    return rintf(y * DELTA);
}

// Fast f32 tanh. Poly (|x|<=0.5): Taylor odd series through x^11,
// rel err <= ~2.5e-7. Exp form else: (E-1)/(E+1) with native exp + NR rcp.
__device__ __forceinline__ float fast_tanh(float x) {
    float ax  = fabsf(x);
    float axc = fminf(ax, 10.0f);
    float E   = __expf(2.0f * axc);
    float num = E - 1.0f;
    float den = E + 1.0f;
    float r0  = __builtin_amdgcn_rcpf(den);
    float r   = r0 * fmaf(-den, r0, 2.0f);      // one Newton step
    float tl  = copysignf(num * r, x);
    float s = x * x;
    float p = fmaf(s, 0.0035921280f, -0.0088632358f);
    p = fmaf(s, p, 0.021869488f);
    p = fmaf(s, p, -0.053968254f);
    p = fmaf(s, p, 0.13333334f);
    p = fmaf(s, p, -0.33333334f);
    float ts = fmaf(x * s, p, x);
    return (ax <= 0.5f) ? ts : tl;
}

// Process one tile resident in LDS (wave-private buffer).
// Top-4 selection rewritten as distinct-key threshold (exact-equivalent to
// the pairwise rank version): rz is integer-valued with |rz| <= 127, so
// K_j = ((uint)|rz_j| << 3) | (7-j) is a distinct 10-bit key and
// K_i > K_j  <=>  "i beats j" under the stable order (|v| desc, index asc).
// Keep j iff K_j is among the 4 largest <=> K_j >= T (T = 4th largest key),
// found via two 4-sorts (5 compare-exchanges each) + 5-candidate merge:
// 4th largest of two desc-sorted quads A,B = max(min(a0,b2), min(a1,b1),
// min(a2,b0), a3, b3).
__device__ __forceinline__ void compute_tile(float* ldsw, int lane, float M, float C) {
    #pragma unroll
    for (int c = 0; c < (CELLS + 63) / 64; ++c) {
        int ci = lane + 64 * c;           // cell id within tile
        if (ci < CELLS) {                 // only masks half of round 4
            int gb = ci / 9;              // compiler emits magic-mul
            int hw = ci - gb * 9;
            float* cell = ldsw + gb * GB_FLOATS + hw;

            float v8[GROUP];
            unsigned K[GROUP];
            #pragma unroll
            for (int j = 0; j < GROUP; ++j) {
                float xx = cell[9 * j];
                float t  = fast_tanh(xx);
                float z  = t * C;
                float rz = rintf(z);                 // numpy round: half-to-even
                float d  = 0.5f - fabsf(z - rz);     // distance to nearest half-int
                if (d < fmaf(2e-6f, fabsf(z), 5e-7f))
                    rz = ref_rz(xx, M);              // cold, bit-exact chain
                v8[j] = rz;
                K[j] = ((unsigned)fabsf(rz) << 3) | (unsigned)(7 - j);
            }

            unsigned s0 = K[0], s1 = K[1], s2 = K[2], s3 = K[3];
            unsigned s4 = K[4], s5 = K[5], s6 = K[6], s7 = K[7];
            // sort s0..s3 descending: CE = (hi,lo)
            #define CE_(x, y) { unsigned _h = umx(x, y), _l = umn(x, y); x = _h; y = _l; }
            CE_(s0, s1) CE_(s2, s3) CE_(s0, s2) CE_(s1, s3) CE_(s1, s2)
            CE_(s4, s5) CE_(s6, s7) CE_(s4, s6) CE_(s5, s7) CE_(s5, s6)
            #undef CE_
            unsigned T = umx(umx(umn(s0, s6), umn(s1, s5)),
                             umx(umn(s2, s4), umx(s3, s7)));

            #pragma unroll
            for (int j = 0; j < GROUP; ++j)
                cell[9 * j] = (K[j] >= T) ? (v8[j] * INV_DELTA) : 0.0f;
        }
    }
}

// ---------------- Kernel 2: quantize + group top-4 mask ----------------
// Double-buffered per-wave tile pipeline:
//   prologue: issue loads for tiles 0,1
//   iter i:   counted-vmcnt wait for tile i -> compute in LDS -> ds_read
//             results to VGPRs -> lgkmcnt(0) -> reissue loads for tile i+2
//             into the freed buffer -> PLAIN coalesced stores of tile i.
// (Nontemporal stores removed: measured r4 showed write drain at 1.6 TB/s
// capping the pipeline; harness fills prove plain streams hit 6.6 TB/s.)
// vmcnt counts BOTH loads and stores (9 each per tile, in-order retirement),
// hence the 9/18/27/18 wait ladder. No other VMEM ops exist in the loop.
__global__ __launch_bounds__(256, 2) void quant_kernel(const float* __restrict__ x,
                             float* __restrict__ out,
                             const unsigned* __restrict__ ws,
                             int n_gb) {
    __shared__ float lds[WPB][2][TILE_F];   // 73,728 B -> 2 blocks/CU
    __shared__ float sM, sC;
    if (threadIdx.x == 0) {
        // M = max|tanh(x)| = tanh(max|x|) (tanh odd+monotone; RNE symmetric)
        float mm = (float)tanh((double)__uint_as_float(*ws));
        sM = mm;
        sC = (float)(127.0 / (double)mm);
    }
    __syncthreads();                      // the only barrier in this kernel
    float M = sM, C = sC;

    const int wv   = threadIdx.x >> 6;
    const int lane = threadIdx.x & 63;
    const int wave_id = blockIdx.x * WPB + wv;   // 0..2047
    // tiles wave_id*NT .. wave_id*NT+NT-1 ; exact fit: 2048*8*32 = 524,288 gb

    const size_t tbase0 = (size_t)wave_id * NT * TILE_F;

    // ---- prologue: stage tiles 0 and 1 ----
    #pragma unroll
    for (int b = 0; b < 2; ++b) {
        const float* src = x + tbase0 + (size_t)b * TILE_F;
        float* ldsw = &lds[wv][b][0];
        #pragma unroll
        for (int k = 0; k < TILE_CH; ++k) {
            __builtin_amdgcn_global_load_lds(
                (__attribute__((address_space(1))) void*)(src + k * 256 + lane * 4),
                (__attribute__((address_space(3))) void*)(ldsw + k * 256),
                16, 0, 0);
        }
    }

    #pragma unroll
    for (int i = 0; i < NT; ++i) {
        // wait for tile i's 9 loads (in-flight beyond them: see ladder)
        if (i == 0)            wait_vmcnt<9>();
        else if (i == 1)       wait_vmcnt<18>();
        else if (i == NT - 1)  wait_vmcnt<18>();
        else                   wait_vmcnt<27>();
        __builtin_amdgcn_sched_barrier(0);

        float* ldsw = &lds[wv][i & 1][0];
        compute_tile(ldsw, lane, M, C);

        // results LDS -> VGPRs (ds ops in-order within a wave; no wait needed
        // between compute's ds_write and these ds_read)
        f32x4 sv[TILE_CH];
        const f32x4* l4 = (const f32x4*)ldsw;
        #pragma unroll
        for (int k = 0; k < TILE_CH; ++k) sv[k] = l4[k * 64 + lane];
        asm volatile("s_waitcnt lgkmcnt(0)" ::: "memory");
        __builtin_amdgcn_sched_barrier(0);

        // reissue: stage tile i+2 into the buffer we just drained
        if (i + 2 < NT) {
            const float* src = x + tbase0 + (size_t)(i + 2) * TILE_F;
            #pragma unroll
            for (int k = 0; k < TILE_CH; ++k) {
                __builtin_amdgcn_global_load_lds(
                    (__attribute__((address_space(1))) void*)(src + k * 256 + lane * 4),
                    (__attribute__((address_space(3))) void*)(ldsw + k * 256),
                    16, 0, 0);
            }
        }

        // plain coalesced stores of tile i (9 x dwordx4 per lane)
        f32x4* dst4 = (f32x4*)(out + tbase0 + (size_t)i * TILE_F);
        #pragma unroll
        for (int k = 0; k < TILE_CH; ++k)
            dst4[k * 64 + lane] = sv[k];
    }
}

extern "C" void kernel_launch(void* const* d_in, const int* in_sizes, int n_in,
                              void* d_out, int out_size, void* d_ws, size_t ws_size,
                              hipStream_t stream) {
    const float* x = (const float*)d_in[0];
    float* out = (float*)d_out;
    unsigned* ws = (unsigned*)d_ws;

    int n = in_sizes[0];                 // 37,748,736
    int n4 = n / 4;
    int n_gb = n / GB_FLOATS;            // 524,288

    hipMemsetAsync(ws, 0, sizeof(unsigned), stream);

    maxabs_kernel<<<2048, 256, 0, stream>>>((const float4*)x, ws, n4);

    int blocks_q = n_gb / (GB_TILE * NT * WPB);   // 512
    quant_kernel<<<blocks_q, 256, 0, stream>>>(x, out, ws, n_gb);
}

// Round 7
// 305.566 us; speedup vs baseline: 1.0635x; 1.0635x over previous
//
#include <hip/hip_runtime.h>
#include <math.h>

// Problem constants (x: [2048, 2048, 3, 3] f32, bits=8)
// channel stride = h*w = 9 floats; group-block = 8 channels * 9 = 72
// consecutive floats; n = 37,748,736 floats = 524,288 group-blocks.
#define HW        9
#define GROUP     8
#define KEEP      4
#define DELTA     127.0f
#define INV_DELTA (1.0f / 127.0f)
#define GB_FLOATS 72

// Wave-tile geometry: each 64-lane wave owns 32 contiguous group-blocks per
// tile (9216 B) and loops over NT tiles. Reg-staged (T14): plain
// global_load_dwordx4 into a double-buffered VGPR bank (prefetch i+1 during
// i), ds_write_b128 into a SINGLE wave-private LDS buffer, compute in LDS,
// coalesced readback + plain stores. No global_load_lds anywhere (r4
// measured that path pinned at ~3.3 TB/s combined while plain-load/store
// kernels on the same chip do 6.3-6.6 TB/s).
#define GB_TILE   32
#define TILE_F    (GB_TILE * GB_FLOATS)   // 2304 floats = 9216 B per tile
#define TILE_CH   (TILE_F / 256)          // 9 chunks: 64 lanes x 16 B
#define CELLS     (GB_TILE * HW)          // 288 cells per tile
#define WPB       4                       // waves per 256-thread block
#define NT        4                       // tiles per wave
// grid: 524288 / (32*4*4) = 1024 blocks. LDS: 4 waves * 9216 = 36,864 B
// -> LDS allows 4 blocks/CU; VGPR (~150 with 2 reg banks) allows 3 -> ~12
// waves/CU, 1.5x r4/r5's 8.

typedef float f32x4 __attribute__((ext_vector_type(4)));

__device__ __forceinline__ unsigned umx(unsigned a, unsigned b) { return a > b ? a : b; }
__device__ __forceinline__ unsigned umn(unsigned a, unsigned b) { return a < b ? a : b; }

// ---------------- Kernel 1: global max|x| ----------------
__global__ void maxabs_kernel(const float4* __restrict__ x, unsigned* __restrict__ ws, int n4) {
    __shared__ float red[4];
    float m = 0.0f;
    int stride = gridDim.x * blockDim.x;
    #pragma unroll 4
    for (int i = blockIdx.x * blockDim.x + threadIdx.x; i < n4; i += stride) {
        float4 v = x[i];
        m = fmaxf(m, fmaxf(fmaxf(fabsf(v.x), fabsf(v.y)),
                           fmaxf(fabsf(v.z), fabsf(v.w))));
    }
    #pragma unroll
    for (int off = 32; off > 0; off >>= 1)
        m = fmaxf(m, __shfl_down(m, off, 64));
    int wave = threadIdx.x >> 6;
    if ((threadIdx.x & 63) == 0) red[wave] = m;
    __syncthreads();
    if (threadIdx.x == 0) {
        float b = fmaxf(fmaxf(red[0], red[1]), fmaxf(red[2], red[3]));
        atomicMax(ws, __float_as_uint(b));   // |x|>=0: float bit order == uint order
    }
}

// Cold bit-exact reference path (identical to the passing kernel):
// t = (float)tanh(double x); y = t/M (f32 div); z = y*127; rint.
__device__ __attribute__((noinline)) float ref_rz(float xx, float M) {
    float td = (float)tanh((double)xx);
    float y  = td / M;
    return rintf(y * DELTA);
}

// Fast f32 tanh. Poly (|x|<=0.5): Taylor odd series through x^11,
// rel err <= ~2.5e-7. Exp form else: (E-1)/(E+1) with native exp + NR rcp.
__device__ __forceinline__ float fast_tanh(float x) {
    float ax  = fabsf(x);
    float axc = fminf(ax, 10.0f);
    float E   = __expf(2.0f * axc);
    float num = E - 1.0f;
    float den = E + 1.0f;
    float r0  = __builtin_amdgcn_rcpf(den);
    float r   = r0 * fmaf(-den, r0, 2.0f);      // one Newton step
    float tl  = copysignf(num * r, x);
    float s = x * x;
    float p = fmaf(s, 0.0035921280f, -0.0088632358f);
    p = fmaf(s, p, 0.021869488f);
    p = fmaf(s, p, -0.053968254f);
    p = fmaf(s, p, 0.13333334f);
    p = fmaf(s, p, -0.33333334f);
    float ts = fmaf(x * s, p, x);
    return (ax <= 0.5f) ? ts : tl;
}

// Process one tile resident in LDS (wave-private buffer).
// Top-4 via distinct-key threshold (exact-equivalent to pairwise rank,
// verified r5): K_j = (|rz_j|<<3)|(7-j); keep j iff K_j >= T (4th-largest),
// via two descending 4-sorts + 5-candidate merge.
__device__ __forceinline__ void compute_tile(float* ldsw, int lane, float M, float C) {
    #pragma unroll
    for (int c = 0; c < (CELLS + 63) / 64; ++c) {
        int ci = lane + 64 * c;           // cell id within tile
        if (ci < CELLS) {                 // only masks half of round 4
            int gb = ci / 9;              // compiler emits magic-mul
            int hw = ci - gb * 9;
            float* cell = ldsw + gb * GB_FLOATS + hw;

            float v8[GROUP];
            unsigned K[GROUP];
            #pragma unroll
            for (int j = 0; j < GROUP; ++j) {
                float xx = cell[9 * j];
                float t  = fast_tanh(xx);
                float z  = t * C;
                float rz = rintf(z);                 // numpy round: half-to-even
                float d  = 0.5f - fabsf(z - rz);     // distance to nearest half-int
                if (d < fmaf(2e-6f, fabsf(z), 5e-7f))
                    rz = ref_rz(xx, M);              // cold, bit-exact chain
                v8[j] = rz;
                K[j] = ((unsigned)fabsf(rz) << 3) | (unsigned)(7 - j);
            }

            unsigned s0 = K[0], s1 = K[1], s2 = K[2], s3 = K[3];
            unsigned s4 = K[4], s5 = K[5], s6 = K[6], s7 = K[7];
            #define CE_(x, y) { unsigned _h = umx(x, y), _l = umn(x, y); x = _h; y = _l; }
            CE_(s0, s1) CE_(s2, s3) CE_(s0, s2) CE_(s1, s3) CE_(s1, s2)
            CE_(s4, s5) CE_(s6, s7) CE_(s4, s6) CE_(s5, s7) CE_(s5, s6)
            #undef CE_
            unsigned T = umx(umx(umn(s0, s6), umn(s1, s5)),
                             umx(umn(s2, s4), umx(s3, s7)));

            #pragma unroll
            for (int j = 0; j < GROUP; ++j)
                cell[9 * j] = (K[j] >= T) ? (v8[j] * INV_DELTA) : 0.0f;
        }
    }
}

// ---------------- Kernel 2: quantize + group top-4 mask ----------------
// Reg-staged pipeline per wave, single LDS buffer:
//   prologue: load tile 0 -> bank A
//   iter i:   load tile i+1 -> other bank (plain dwordx4, prefetch)
//             ds_write bank(i) -> LDS   (compiler inserts exact vmcnt wait
//                                        on the loaded regs; prefetch loads
//                                        stay outstanding)
//             compute in LDS            (ds ops in-order within a wave: the
//                                        reads see this iter's writes, and
//                                        next iter's writes can't pass this
//                                        iter's reads -- r4/r5-verified)
//             coalesced LDS->VGPR->global store (compiler inserts lgkmcnt)
// All waitcnts are compiler-derived from register dependencies -- no hand
// ladder. sched_barrier(0) pins phase order only.
__global__ __launch_bounds__(256, 3) void quant_kernel(const float* __restrict__ x,
                             float* __restrict__ out,
                             const unsigned* __restrict__ ws,
                             int n_gb) {
    __shared__ float lds[WPB][TILE_F];   // 36,864 B
    __shared__ float sM, sC;
    if (threadIdx.x == 0) {
        // M = max|tanh(x)| = tanh(max|x|) (tanh odd+monotone; RNE symmetric)
        float mm = (float)tanh((double)__uint_as_float(*ws));
        sM = mm;
        sC = (float)(127.0 / (double)mm);
    }
    __syncthreads();                      // the only barrier in this kernel
    float M = sM, C = sC;

    const int wv   = threadIdx.x >> 6;
    const int lane = threadIdx.x & 63;
    const int wave_id = blockIdx.x * WPB + wv;   // 0..4095
    // exact fit: 1024 blocks * 4 waves * 4 tiles * 32 gb = 524,288

    const size_t tbase0 = (size_t)wave_id * NT * TILE_F;
    float* ldsw = &lds[wv][0];
    f32x4* l4 = (f32x4*)ldsw;

    f32x4 ra[TILE_CH], rb[TILE_CH];

    // prologue: tile 0 -> bank A
    {
        const f32x4* s4 = (const f32x4*)(x + tbase0);
        #pragma unroll
        for (int k = 0; k < TILE_CH; ++k) ra[k] = s4[k * 64 + lane];
    }

    #pragma unroll
    for (int i = 0; i < NT; ++i) {
        f32x4* cur = (i & 1) ? rb : ra;   // i is compile-time (unrolled)
        f32x4* nxt = (i & 1) ? ra : rb;

        // prefetch tile i+1 into the other bank
        if (i + 1 < NT) {
            const f32x4* sn = (const f32x4*)(x + tbase0 + (size_t)(i + 1) * TILE_F);
            #pragma unroll
            for (int k = 0; k < TILE_CH; ++k) nxt[k] = sn[k * 64 + lane];
        }
        __builtin_amdgcn_sched_barrier(0);

        // stage bank(i) -> LDS (coalesced b128 writes, linear layout)
        #pragma unroll
        for (int k = 0; k < TILE_CH; ++k) l4[k * 64 + lane] = cur[k];
        __builtin_amdgcn_sched_barrier(0);

        compute_tile(ldsw, lane, M, C);
        __builtin_amdgcn_sched_barrier(0);

        // coalesced LDS -> global (per-chunk temp keeps reg pressure low)
        f32x4* dst4 = (f32x4*)(out + tbase0 + (size_t)i * TILE_F);
        #pragma unroll
        for (int k = 0; k < TILE_CH; ++k)
            dst4[k * 64 + lane] = l4[k * 64 + lane];
        __builtin_amdgcn_sched_barrier(0);
    }
}

extern "C" void kernel_launch(void* const* d_in, const int* in_sizes, int n_in,
                              void* d_out, int out_size, void* d_ws, size_t ws_size,
                              hipStream_t stream) {
    const float* x = (const float*)d_in[0];
    float* out = (float*)d_out;
    unsigned* ws = (unsigned*)d_ws;

    int n = in_sizes[0];                 // 37,748,736
    int n4 = n / 4;
    int n_gb = n / GB_FLOATS;            // 524,288

    hipMemsetAsync(ws, 0, sizeof(unsigned), stream);

    maxabs_kernel<<<2048, 256, 0, stream>>>((const float4*)x, ws, n4);

    int blocks_q = n_gb / (GB_TILE * NT * WPB);   // 1024
    quant_kernel<<<blocks_q, 256, 0, stream>>>(x, out, ws, n_gb);
}